// Round 3
// baseline (2581.644 us; speedup 1.0000x reference)
//
#include <hip/hip_runtime.h>

// LSTM  B=64 T=512 D=256 H=512, fp32 in/out.
// Persistent kernel: 4 clusters x 32 WGs, 16 batches/cluster, 16 h-cols/WG.
// R3: tag-in-data sync -- h elements stored as u64 {tag,hi16|lo16} via relaxed
// agent atomics; consumers poll their own gather loads (no flags, no drain,
// no fences). B-fragments hoisted to registers (96 VGPR/wave); w_lds reused
// as partial-C buffer. 2 barriers/step.

#define B_   64
#define T_   512
#define D_   256
#define H_   512
#define NCL  4            // clusters
#define WPC  32           // workgroups per cluster
#define BPC  16           // batches per cluster
#define NKT  24           // K tiles of 32
#define NCT  4            // col tiles of 16 (64 gemm cols = 16 hc x 4 gates)
#define ZPAD 776          // padded z row length in ushorts

typedef __attribute__((ext_vector_type(8)))  short  short8;
typedef __attribute__((ext_vector_type(4)))  float  f32x4;
typedef __attribute__((ext_vector_type(4)))  float  float4_;
typedef unsigned short ushort_t;
typedef unsigned int   uint_t;
typedef unsigned long long u64_t;

__device__ __forceinline__ ushort_t f2bf(float f) {           // RNE f32->bf16
    unsigned int u = __float_as_uint(f);
    u += 0x7FFFu + ((u >> 16) & 1u);
    return (ushort_t)(u >> 16);
}
__device__ __forceinline__ float bf2f(ushort_t h) {
    return __uint_as_float(((unsigned int)h) << 16);
}
__device__ __forceinline__ float sigm_(float x) { return 1.0f / (1.0f + __expf(-x)); }
__device__ __forceinline__ float tanh_(float x) {
    float a = fabsf(x);
    float e = __expf(-2.0f * a);
    float r = (1.0f - e) / (1.0f + e);
    return copysignf(r, x);
}

__global__ __launch_bounds__(256, 1)
void lstm_persistent(const float* __restrict__ x,
                     const float* __restrict__ Wf, const float* __restrict__ bf_,
                     const float* __restrict__ Wi, const float* __restrict__ bi_,
                     const float* __restrict__ Wo, const float* __restrict__ bo_,
                     const float* __restrict__ Wc, const float* __restrict__ bc_,
                     float* __restrict__ out,
                     u64_t* __restrict__ hpack)   // [2][NCL][BPC][H_] u64 {tag,hi|lo}
{
    __shared__ ushort_t w_lds[NCT * NKT * 512];   // 98304 B; pC after prologue
    __shared__ ushort_t z_hi[16 * ZPAD];          // 24832 B
    __shared__ ushort_t z_lo[16 * ZPAD];          // 24832 B
    __shared__ float    bias_lds[64];             //   256 B

    const int tid  = threadIdx.x;
    const int lane = tid & 63;
    const int wv   = tid >> 6;          // wave 0..3
    const int cl   = blockIdx.x >> 5;   // cluster 0..3
    const int w    = blockIdx.x & 31;   // wg-in-cluster 0..31
    const int b0   = cl * BPC;          // first batch
    const int hc0  = w * 16;            // first h-col (global)

    // ---- one-time: repack W slice (fp32 global -> bf16 LDS, B-frag order) ----
    // frag: lane l holds B[k = kt*32 + (l>>4)*8 + j][n = ct*16 + (l&15)], j=0..7
    for (int idx = tid; idx < NCT * NKT * 64; idx += 256) {
        int blk   = idx >> 6;           // 0..95
        int ln    = idx & 63;
        int ct    = blk / NKT;
        int kt    = blk % NKT;
        int col16 = ln & 15;
        int kc    = ln >> 4;
        int j     = ct * 16 + col16;    // gemm col 0..63  (j = hc*4 + g)
        int hc    = j >> 2, g = j & 3;
        int gcol  = hc0 + hc;
        const float* Wsrc = (g == 0) ? Wf : ((g == 1) ? Wi : ((g == 2) ? Wo : Wc));
        int krow0 = kt * 32 + kc * 8;
        short8 v;
#pragma unroll
        for (int jj = 0; jj < 8; ++jj)
            v[jj] = (short)f2bf(Wsrc[(size_t)(krow0 + jj) * H_ + gcol]);
        *(short8*)(w_lds + blk * 512 + ln * 8) = v;
    }
    if (tid < 64) {
        int g = tid & 3, hc = tid >> 2;
        const float* bsrc = (g == 0) ? bf_ : ((g == 1) ? bi_ : ((g == 2) ? bo_ : bc_));
        bias_lds[tid] = bsrc[hc0 + hc];
    }
    __syncthreads();

    // ---- hoist this wave's 24 B-fragments into registers (96 VGPR) ----
    short8 Bf[NCT][6];
#pragma unroll
    for (int ct = 0; ct < NCT; ++ct)
#pragma unroll
        for (int k6 = 0; k6 < 6; ++k6)
            Bf[ct][k6] = *(const short8*)(w_lds + (ct * NKT + wv * 6 + k6) * 512 + lane * 8);
    // w_lds is dead from here; reuse as partial-C (first write is after
    // barrier (1) of t=0, so all waves' Bf reads are complete).
    float* pC = (float*)w_lds;          // 16 KB used: [16][256] f32

    // ---- persistent state ----
    float c_reg = 0.0f;                 // cell state for (batch=tid>>4, hc=tid&15)
    const int bx = tid & 15, ch = tid >> 4;   // z-build mapping
    const float* xbase = x + (size_t)(b0 + bx) * (T_ * D_) + ch * 16;

    // prefetch x for t=0
    float4_ xr0, xr1, xr2, xr3;
    {
        const float4_* p = (const float4_*)xbase;
        xr0 = p[0]; xr1 = p[1]; xr2 = p[2]; xr3 = p[3];
    }

    // zero the h-part of z (t=0 uses h=0)
#pragma unroll
    for (int q = 0; q < 32; ++q) {
        int zo = (q >> 1) * ZPAD + 256 + (q & 1) * 256 + tid;
        z_hi[zo] = 0; z_lo[zo] = 0;
    }

    const int l15 = lane & 15, lk = lane >> 4;
    const ushort_t* zh_frag = z_hi + l15 * ZPAD + lk * 8;
    const ushort_t* zl_frag = z_lo + l15 * ZPAD + lk * 8;

    const int gb = tid >> 4, ghc = tid & 15;   // gates mapping
    const int ctg = ghc >> 2;

    for (int t = 0; t < T_; ++t) {
        // ---- (a) build z x-part from prefetched regs (independent of h) ----
        {
            ushort_t hp[16], lp[16];
#pragma unroll
            for (int e = 0; e < 4; ++e) {
                float xf; ushort_t hb;
                xf = xr0[e]; hb = f2bf(xf); hp[e]      = hb; lp[e]      = f2bf(xf - bf2f(hb));
                xf = xr1[e]; hb = f2bf(xf); hp[4 + e]  = hb; lp[4 + e]  = f2bf(xf - bf2f(hb));
                xf = xr2[e]; hb = f2bf(xf); hp[8 + e]  = hb; lp[8 + e]  = f2bf(xf - bf2f(hb));
                xf = xr3[e]; hb = f2bf(xf); hp[12 + e] = hb; lp[12 + e] = f2bf(xf - bf2f(hb));
            }
            short8 a0, a1, b0v, b1v;
#pragma unroll
            for (int e = 0; e < 8; ++e) {
                a0[e] = (short)hp[e]; a1[e] = (short)hp[8 + e];
                b0v[e] = (short)lp[e]; b1v[e] = (short)lp[8 + e];
            }
            ushort_t* zh = z_hi + bx * ZPAD + ch * 16;
            ushort_t* zl = z_lo + bx * ZPAD + ch * 16;
            ((short8*)zh)[0] = a0; ((short8*)zh)[1] = a1;
            ((short8*)zl)[0] = b0v; ((short8*)zl)[1] = b1v;
        }

        // ---- (b) gather cluster h(t): tag-polled u64 loads (no flags) ----
        if (t > 0) {
            const u64_t* hsrc = hpack + (size_t)((t & 1) * NCL + cl) * (BPC * H_);
            const uint_t want = (uint_t)t;
            uint_t mask = 0xffffffffu;    // stale slots (per-thread)
            do {
                u64_t v[32];
#pragma unroll
                for (int q = 0; q < 32; ++q)
                    if (mask & (1u << q))
                        v[q] = __hip_atomic_load(hsrc + q * 256 + tid,
                                                 __ATOMIC_RELAXED, __HIP_MEMORY_SCOPE_AGENT);
#pragma unroll
                for (int q = 0; q < 32; ++q)
                    if ((mask & (1u << q)) && (uint_t)(v[q] >> 32) == want) {
                        int zo = (q >> 1) * ZPAD + 256 + (q & 1) * 256 + tid;
                        uint_t d = (uint_t)v[q];
                        z_hi[zo] = (ushort_t)(d >> 16);
                        z_lo[zo] = (ushort_t)(d & 0xffffu);
                        mask &= ~(1u << q);
                    }
            } while (mask);
        }
        __syncthreads();   // (1) z ready; also protects pC reuse across iters

        // ---- prefetch x for t+1 (latency hides under MFMA+gates) ----
        if (t + 1 < T_) {
            const float4_* p = (const float4_*)(xbase + (size_t)(t + 1) * D_);
            xr0 = p[0]; xr1 = p[1]; xr2 = p[2]; xr3 = p[3];
        }

        // ---- (c) MFMA: waves split K (6 kt each), B-frags from registers ----
        f32x4 acc0 = {0.f, 0.f, 0.f, 0.f};
        f32x4 acc1 = {0.f, 0.f, 0.f, 0.f};
        f32x4 acc2 = {0.f, 0.f, 0.f, 0.f};
        f32x4 acc3 = {0.f, 0.f, 0.f, 0.f};
        const int kt0 = wv * 6;
#pragma unroll
        for (int k6 = 0; k6 < 6; ++k6) {
            const int kt = kt0 + k6;
            short8 ah = *(const short8*)(zh_frag + kt * 32);
            short8 al = *(const short8*)(zl_frag + kt * 32);
            acc0 = __builtin_amdgcn_mfma_f32_16x16x32_bf16(ah, Bf[0][k6], acc0, 0, 0, 0);
            acc0 = __builtin_amdgcn_mfma_f32_16x16x32_bf16(al, Bf[0][k6], acc0, 0, 0, 0);
            acc1 = __builtin_amdgcn_mfma_f32_16x16x32_bf16(ah, Bf[1][k6], acc1, 0, 0, 0);
            acc1 = __builtin_amdgcn_mfma_f32_16x16x32_bf16(al, Bf[1][k6], acc1, 0, 0, 0);
            acc2 = __builtin_amdgcn_mfma_f32_16x16x32_bf16(ah, Bf[2][k6], acc2, 0, 0, 0);
            acc2 = __builtin_amdgcn_mfma_f32_16x16x32_bf16(al, Bf[2][k6], acc2, 0, 0, 0);
            acc3 = __builtin_amdgcn_mfma_f32_16x16x32_bf16(ah, Bf[3][k6], acc3, 0, 0, 0);
            acc3 = __builtin_amdgcn_mfma_f32_16x16x32_bf16(al, Bf[3][k6], acc3, 0, 0, 0);
        }

        // ---- write per-wave partial C (pC disjoint from z: no barrier needed) ----
#pragma unroll
        for (int i = 0; i < 4; ++i) {
            int r = (lk * 4 + i) * 16 + l15;
            pC[(wv * 4 + 0) * 256 + r] = acc0[i];
            pC[(wv * 4 + 1) * 256 + r] = acc1[i];
            pC[(wv * 4 + 2) * 256 + r] = acc2[i];
            pC[(wv * 4 + 3) * 256 + r] = acc3[i];
        }
        __syncthreads();   // (2) pC ready

        // ---- gates + state update: thread -> (batch=gb, hc=ghc) ----
        float hout;
        {
            float pre[4];
#pragma unroll
            for (int g = 0; g < 4; ++g) {
                float s = bias_lds[ghc * 4 + g];
                const int col = (ghc & 3) * 4 + g;
#pragma unroll
                for (int wv2 = 0; wv2 < 4; ++wv2)
                    s += pC[(wv2 * 4 + ctg) * 256 + gb * 16 + col];
                pre[g] = s;
            }
            float fg = sigm_(pre[0]);
            float ig = sigm_(pre[1]);
            float og = sigm_(pre[2]);
            float cc = tanh_(pre[3]);
            c_reg = fmaf(c_reg, fg, cc * ig);
            hout = og * tanh_(c_reg);

            // publish h(t+1) with embedded tag -- fire and forget
            uint_t hb = (uint_t)f2bf(hout);
            uint_t lb = (uint_t)f2bf(hout - bf2f((ushort_t)hb));
            u64_t pk = ((u64_t)(uint_t)(t + 1) << 32) | ((u64_t)hb << 16) | lb;
            size_t ho = (size_t)(((t + 1) & 1) * NCL + cl) * (BPC * H_)
                      + (size_t)gb * H_ + hc0 + ghc;
            __hip_atomic_store(hpack + ho, pk,
                               __ATOMIC_RELAXED, __HIP_MEMORY_SCOPE_AGENT);
        }

        // ---- deferred out store (off the critical sync path) ----
        out[((size_t)(b0 + gb) * T_ + t) * H_ + hc0 + ghc] = hout;
    }
}

extern "C" void kernel_launch(void* const* d_in, const int* in_sizes, int n_in,
                              void* d_out, int out_size, void* d_ws, size_t ws_size,
                              hipStream_t stream) {
    const float* x  = (const float*)d_in[0];
    const float* Wf = (const float*)d_in[1];
    const float* bf = (const float*)d_in[2];
    const float* Wi = (const float*)d_in[3];
    const float* bi = (const float*)d_in[4];
    const float* Wo = (const float*)d_in[5];
    const float* bo = (const float*)d_in[6];
    const float* Wc = (const float*)d_in[7];
    const float* bc = (const float*)d_in[8];
    float* out = (float*)d_out;

    // workspace: hpack [2][NCL][BPC][H_] u64 = 512 KB
    u64_t* hpack = (u64_t*)d_ws;
    hipMemsetAsync(d_ws, 0, (size_t)2 * NCL * BPC * H_ * sizeof(u64_t), stream);

    lstm_persistent<<<dim3(NCL * WPC), dim3(256), 0, stream>>>(
        x, Wf, bf, Wi, bi, Wo, bo, Wc, bc, out, hpack);
}

// Round 4
// 2401.742 us; speedup vs baseline: 1.0749x; 1.0749x over previous
//
#include <hip/hip_runtime.h>

// LSTM  B=64 T=512 D=256 H=512, fp32 in/out.
// Persistent kernel: 4 clusters x 32 WGs, 16 batches/cluster, 16 h-cols/WG.
// R4: tag-in-data with u32 {bf16(h)<<16 | tag16} -- register-cheap gather
// (32 VGPR), speculative early issue (loads fly during out-store + z-build),
// per-slot retry. x keeps bf16 hi/lo planes; h plain bf16; c f32.
// No flags, no fences, no vmcnt drains. 2 barriers/step. B-frags from LDS.

#define B_   64
#define T_   512
#define D_   256
#define H_   512
#define NCL  4            // clusters
#define WPC  32           // workgroups per cluster
#define BPC  16           // batches per cluster
#define NKT  24           // K tiles of 32 (24*32 = 768 = D_+H_)
#define NCT  4            // col tiles of 16 (64 gemm cols = 16 hc x 4 gates)
#define ZPAD 776          // z_main row length in ushorts (768 + 8 pad)
#define XLP  264          // z_xlo row length in ushorts (256 + 8 pad)

typedef __attribute__((ext_vector_type(8)))  short  short8;
typedef __attribute__((ext_vector_type(4)))  float  f32x4;
typedef __attribute__((ext_vector_type(4)))  float  float4_;
typedef unsigned short ushort_t;
typedef unsigned int   uint_t;

__device__ __forceinline__ ushort_t f2bf(float f) {           // RNE f32->bf16
    unsigned int u = __float_as_uint(f);
    u += 0x7FFFu + ((u >> 16) & 1u);
    return (ushort_t)(u >> 16);
}
__device__ __forceinline__ float bf2f(ushort_t h) {
    return __uint_as_float(((unsigned int)h) << 16);
}
__device__ __forceinline__ float sigm_(float x) { return 1.0f / (1.0f + __expf(-x)); }
__device__ __forceinline__ float tanh_(float x) {
    float a = fabsf(x);
    float e = __expf(-2.0f * a);
    float r = (1.0f - e) / (1.0f + e);
    return copysignf(r, x);
}

// build x-part of z: hi plane -> z_main cols [0,256), lo plane -> z_xlo
__device__ __forceinline__ void zbuild_x(ushort_t* z_main, ushort_t* z_xlo,
                                         int bx, int ch,
                                         float4_ xr0, float4_ xr1,
                                         float4_ xr2, float4_ xr3)
{
    ushort_t hp[16], lp[16];
#pragma unroll
    for (int e = 0; e < 4; ++e) {
        float xf; ushort_t hb;
        xf = xr0[e]; hb = f2bf(xf); hp[e]      = hb; lp[e]      = f2bf(xf - bf2f(hb));
        xf = xr1[e]; hb = f2bf(xf); hp[4 + e]  = hb; lp[4 + e]  = f2bf(xf - bf2f(hb));
        xf = xr2[e]; hb = f2bf(xf); hp[8 + e]  = hb; lp[8 + e]  = f2bf(xf - bf2f(hb));
        xf = xr3[e]; hb = f2bf(xf); hp[12 + e] = hb; lp[12 + e] = f2bf(xf - bf2f(hb));
    }
    short8 a0, a1, b0v, b1v;
#pragma unroll
    for (int e = 0; e < 8; ++e) {
        a0[e] = (short)hp[e]; a1[e] = (short)hp[8 + e];
        b0v[e] = (short)lp[e]; b1v[e] = (short)lp[8 + e];
    }
    ushort_t* zh = z_main + bx * ZPAD + ch * 16;
    ushort_t* zl = z_xlo  + bx * XLP  + ch * 16;
    ((short8*)zh)[0] = a0; ((short8*)zh)[1] = a1;
    ((short8*)zl)[0] = b0v; ((short8*)zl)[1] = b1v;
}

__global__ __launch_bounds__(256, 1)
void lstm_persistent(const float* __restrict__ x,
                     const float* __restrict__ Wf, const float* __restrict__ bf_,
                     const float* __restrict__ Wi, const float* __restrict__ bi_,
                     const float* __restrict__ Wo, const float* __restrict__ bo_,
                     const float* __restrict__ Wc, const float* __restrict__ bc_,
                     float* __restrict__ out,
                     uint_t* __restrict__ hpack)   // [2][NCL][BPC][H_] u32 {bf16<<16|tag}
{
    __shared__ ushort_t w_lds[NCT * NKT * 512];   // 98304 B
    __shared__ ushort_t z_main[16 * ZPAD];        // 24832 B ([x_hi | h] 768 cols)
    __shared__ ushort_t z_xlo[16 * XLP];          //  8448 B (x lo plane)
    __shared__ float    pC[16 * 256];             // 16384 B partial C
    __shared__ float    bias_lds[64];             //   256 B   (total 148224)

    const int tid  = threadIdx.x;
    const int lane = tid & 63;
    const int wv   = tid >> 6;          // wave 0..3
    const int cl   = blockIdx.x >> 5;   // cluster 0..3
    const int w    = blockIdx.x & 31;   // wg-in-cluster 0..31
    const int b0   = cl * BPC;          // first batch
    const int hc0  = w * 16;            // first h-col (global)

    // ---- one-time: repack W slice (fp32 global -> bf16 LDS, B-frag order) ----
    // frag: lane l holds B[k = kt*32 + (l>>4)*8 + j][n = ct*16 + (l&15)], j=0..7
    for (int idx = tid; idx < NCT * NKT * 64; idx += 256) {
        int blk   = idx >> 6;           // 0..95
        int ln    = idx & 63;
        int ct    = blk / NKT;
        int kt    = blk % NKT;
        int col16 = ln & 15;
        int kc    = ln >> 4;
        int j     = ct * 16 + col16;    // gemm col 0..63  (j = hc*4 + g)
        int hc    = j >> 2, g = j & 3;
        int gcol  = hc0 + hc;
        const float* Wsrc = (g == 0) ? Wf : ((g == 1) ? Wi : ((g == 2) ? Wo : Wc));
        int krow0 = kt * 32 + kc * 8;
        short8 v;
#pragma unroll
        for (int jj = 0; jj < 8; ++jj)
            v[jj] = (short)f2bf(Wsrc[(size_t)(krow0 + jj) * H_ + gcol]);
        *(short8*)(w_lds + blk * 512 + ln * 8) = v;
    }
    if (tid < 64) {
        int g = tid & 3, hc = tid >> 2;
        const float* bsrc = (g == 0) ? bf_ : ((g == 1) ? bi_ : ((g == 2) ? bo_ : bc_));
        bias_lds[tid] = bsrc[hc0 + hc];
    }

    // ---- persistent state ----
    float c_reg = 0.0f;                 // cell state for (batch=tid>>4, hc=tid&15)
    const int bx = tid & 15, ch = tid >> 4;   // z-build mapping
    const float* xbase = x + (size_t)(b0 + bx) * (T_ * D_) + ch * 16;

    // prefetch x(0) and build z(0): x part + h = 0
    float4_ xr0, xr1, xr2, xr3;
    {
        const float4_* p = (const float4_*)xbase;
        xr0 = p[0]; xr1 = p[1]; xr2 = p[2]; xr3 = p[3];
    }
    zbuild_x(z_main, z_xlo, bx, ch, xr0, xr1, xr2, xr3);
#pragma unroll
    for (int q = 0; q < 32; ++q)
        z_main[(q >> 1) * ZPAD + 256 + (q & 1) * 256 + tid] = 0;
    __syncthreads();   // z(0) ready (also covers w_lds/bias prologue)

    const int l15 = lane & 15, lk = lane >> 4;
    const ushort_t* zrow  = z_main + l15 * ZPAD + lk * 8;
    const ushort_t* xlrow = z_xlo  + l15 * XLP  + lk * 8;
    const ushort_t* wfrag = w_lds + lane * 8;

    const int gb = tid >> 4, ghc = tid & 15;   // gates mapping
    const int ctg = ghc >> 2;
    const int kx0 = 2 * wv;        // this wave's x K-tiles: kx0, kx0+1
    const int kh0 = 8 + 4 * wv;    // this wave's h K-tiles: kh0..kh0+3

    for (int t = 0; t < T_; ++t) {
        // ---- prefetch x(t+1) (consumed in z-build after gates) ----
        if (t + 1 < T_) {
            const float4_* p = (const float4_*)(xbase + (size_t)(t + 1) * D_);
            xr0 = p[0]; xr1 = p[1]; xr2 = p[2]; xr3 = p[3];
        }

        // ---- A-frags for this wave (8 x b128), then MFMA over 4 col-tiles ----
        short8 axh0 = *(const short8*)(zrow  + (kx0    ) * 32);
        short8 axh1 = *(const short8*)(zrow  + (kx0 + 1) * 32);
        short8 axl0 = *(const short8*)(xlrow + (kx0    ) * 32);
        short8 axl1 = *(const short8*)(xlrow + (kx0 + 1) * 32);
        short8 ah0  = *(const short8*)(zrow  + (kh0    ) * 32);
        short8 ah1  = *(const short8*)(zrow  + (kh0 + 1) * 32);
        short8 ah2  = *(const short8*)(zrow  + (kh0 + 2) * 32);
        short8 ah3  = *(const short8*)(zrow  + (kh0 + 3) * 32);

        f32x4 acc0 = {0.f, 0.f, 0.f, 0.f};
        f32x4 acc1 = {0.f, 0.f, 0.f, 0.f};
        f32x4 acc2 = {0.f, 0.f, 0.f, 0.f};
        f32x4 acc3 = {0.f, 0.f, 0.f, 0.f};
#define CT_BODY(CT, ACC)                                                          \
        {                                                                         \
            short8 bb;                                                            \
            bb = *(const short8*)(wfrag + ((CT) * NKT + kx0    ) * 512);          \
            ACC = __builtin_amdgcn_mfma_f32_16x16x32_bf16(axh0, bb, ACC, 0, 0, 0);\
            ACC = __builtin_amdgcn_mfma_f32_16x16x32_bf16(axl0, bb, ACC, 0, 0, 0);\
            bb = *(const short8*)(wfrag + ((CT) * NKT + kx0 + 1) * 512);          \
            ACC = __builtin_amdgcn_mfma_f32_16x16x32_bf16(axh1, bb, ACC, 0, 0, 0);\
            ACC = __builtin_amdgcn_mfma_f32_16x16x32_bf16(axl1, bb, ACC, 0, 0, 0);\
            bb = *(const short8*)(wfrag + ((CT) * NKT + kh0    ) * 512);          \
            ACC = __builtin_amdgcn_mfma_f32_16x16x32_bf16(ah0, bb, ACC, 0, 0, 0); \
            bb = *(const short8*)(wfrag + ((CT) * NKT + kh0 + 1) * 512);          \
            ACC = __builtin_amdgcn_mfma_f32_16x16x32_bf16(ah1, bb, ACC, 0, 0, 0); \
            bb = *(const short8*)(wfrag + ((CT) * NKT + kh0 + 2) * 512);          \
            ACC = __builtin_amdgcn_mfma_f32_16x16x32_bf16(ah2, bb, ACC, 0, 0, 0); \
            bb = *(const short8*)(wfrag + ((CT) * NKT + kh0 + 3) * 512);          \
            ACC = __builtin_amdgcn_mfma_f32_16x16x32_bf16(ah3, bb, ACC, 0, 0, 0); \
        }
        CT_BODY(0, acc0)
        CT_BODY(1, acc1)
        CT_BODY(2, acc2)
        CT_BODY(3, acc3)
#undef CT_BODY

        // ---- write per-wave partial C (C layout: col=lane&15, row=(lane>>4)*4+i) ----
#pragma unroll
        for (int i = 0; i < 4; ++i) {
            int r = (lk * 4 + i) * 16 + l15;
            pC[(wv * 4 + 0) * 256 + r] = acc0[i];
            pC[(wv * 4 + 1) * 256 + r] = acc1[i];
            pC[(wv * 4 + 2) * 256 + r] = acc2[i];
            pC[(wv * 4 + 3) * 256 + r] = acc3[i];
        }
        __syncthreads();   // (B) pC ready; z reads of step t complete

        // ---- gates + state update: thread -> (batch=gb, hc=ghc) ----
        float hout;
        {
            float pre[4];
#pragma unroll
            for (int g = 0; g < 4; ++g) {
                float s = bias_lds[ghc * 4 + g];
                const int col = (ghc & 3) * 4 + g;
#pragma unroll
                for (int wv2 = 0; wv2 < 4; ++wv2)
                    s += pC[(wv2 * 4 + ctg) * 256 + gb * 16 + col];
                pre[g] = s;
            }
            float fg = sigm_(pre[0]);
            float ig = sigm_(pre[1]);
            float og = sigm_(pre[2]);
            float cc = tanh_(pre[3]);
            c_reg = fmaf(c_reg, fg, cc * ig);
            hout = og * tanh_(c_reg);
        }

        // ---- publish h(t+1) tagged; fire-and-forget ----
        {
            uint_t hb = (uint_t)f2bf(hout);
            uint_t pk = (hb << 16) | (uint_t)((t + 1) & 0xffff);
            size_t ho = (size_t)(((t + 1) & 1) * NCL + cl) * (BPC * H_)
                      + (size_t)gb * H_ + hc0 + ghc;
            __hip_atomic_store(hpack + ho, pk,
                               __ATOMIC_RELAXED, __HIP_MEMORY_SCOPE_AGENT);
        }

        if (t + 1 < T_) {
            // ---- speculative gather issue for h(t+1): 32 coalesced u32 ----
            const uint_t* hsrc = hpack + (size_t)(((t + 1) & 1) * NCL + cl) * (BPC * H_);
            uint_t vv[32];
#pragma unroll
            for (int q = 0; q < 32; ++q)
                vv[q] = __hip_atomic_load(hsrc + q * 256 + tid,
                                          __ATOMIC_RELAXED, __HIP_MEMORY_SCOPE_AGENT);

            // ---- z-build x(t+1) while gather loads are in flight ----
            zbuild_x(z_main, z_xlo, bx, ch, xr0, xr1, xr2, xr3);

            // ---- check tags; retry stale slots only ----
            const uint_t want = (uint_t)((t + 1) & 0xffff);
            uint_t mask = 0xffffffffu;
            for (;;) {
#pragma unroll
                for (int q = 0; q < 32; ++q)
                    if ((mask & (1u << q)) && (vv[q] & 0xffffu) == want) {
                        z_main[(q >> 1) * ZPAD + 256 + (q & 1) * 256 + tid] =
                            (ushort_t)(vv[q] >> 16);
                        mask &= ~(1u << q);
                    }
                if (!mask) break;
#pragma unroll
                for (int q = 0; q < 32; ++q)
                    if (mask & (1u << q))
                        vv[q] = __hip_atomic_load(hsrc + q * 256 + tid,
                                                  __ATOMIC_RELAXED, __HIP_MEMORY_SCOPE_AGENT);
            }
        }

        // ---- deferred out store (off the critical path, after gather issue) ----
        out[((size_t)(b0 + gb) * T_ + t) * H_ + hc0 + ghc] = hout;

        __syncthreads();   // (A) z(t+1) ready; pC free for overwrite
    }
}

extern "C" void kernel_launch(void* const* d_in, const int* in_sizes, int n_in,
                              void* d_out, int out_size, void* d_ws, size_t ws_size,
                              hipStream_t stream) {
    const float* x  = (const float*)d_in[0];
    const float* Wf = (const float*)d_in[1];
    const float* bf = (const float*)d_in[2];
    const float* Wi = (const float*)d_in[3];
    const float* bi = (const float*)d_in[4];
    const float* Wo = (const float*)d_in[5];
    const float* bo = (const float*)d_in[6];
    const float* Wc = (const float*)d_in[7];
    const float* bc = (const float*)d_in[8];
    float* out = (float*)d_out;

    // workspace: hpack [2][NCL][BPC][H_] u32 = 256 KB
    uint_t* hpack = (uint_t*)d_ws;
    hipMemsetAsync(d_ws, 0, (size_t)2 * NCL * BPC * H_ * sizeof(uint_t), stream);

    lstm_persistent<<<dim3(NCL * WPC), dim3(256), 0, stream>>>(
        x, Wf, bf, Wi, bi, Wo, bo, Wc, bc, out, hpack);
}

// Round 5
// 2213.848 us; speedup vs baseline: 1.1661x; 1.0849x over previous
//
#include <hip/hip_runtime.h>

// LSTM  B=64 T=512 D=256 H=512, fp32 in/out.
// Persistent kernel: 4 clusters x 32 WGs, 16 batches/cluster, 16 h-cols/WG.
// R5: wave-owns-col-tile (no cross-wave reduce, no pC), 1 barrier/step,
// z ping-pong in LDS (wave skew <=1 enforced by the h all-to-all itself),
// in-wave gate transpose via LDS bounce + lgkmcnt, tag-in-data h exchange
// with sleep-paced discovery, coalesced publish layout [slot][cl][h][b].
// x single bf16 plane; W bf16 (B-frags hoisted to VGPRs); c fp32 in-reg.

#define B_   64
#define T_   512
#define D_   256
#define H_   512
#define NCL  4            // clusters
#define WPC  32           // workgroups per cluster
#define BPC  16           // batches per cluster
#define NKT  24           // K tiles of 32 (24*32 = 768 = D_+H_)
#define ZPAD 776          // z row length in ushorts (768 + 8 pad)
#define SLEEP_PRE   13    // ~350 ns: cover store->invalidate propagation
#define SLEEP_RETRY 3     // ~80 ns between retry rounds

typedef __attribute__((ext_vector_type(8)))  short  short8;
typedef __attribute__((ext_vector_type(4)))  float  f32x4;
typedef __attribute__((ext_vector_type(4)))  float  float4_;
typedef unsigned short ushort_t;
typedef unsigned int   uint_t;

__device__ __forceinline__ ushort_t f2bf(float f) {           // RNE f32->bf16
    unsigned int u = __float_as_uint(f);
    u += 0x7FFFu + ((u >> 16) & 1u);
    return (ushort_t)(u >> 16);
}
__device__ __forceinline__ float sigm_(float x) { return 1.0f / (1.0f + __expf(-x)); }
__device__ __forceinline__ float tanh_(float x) {
    float a = fabsf(x);
    float e = __expf(-2.0f * a);
    float r = (1.0f - e) / (1.0f + e);
    return copysignf(r, x);
}

// build x-part of z (single bf16 plane): thread (bx,ch) -> row bx, cols ch*16..+16
__device__ __forceinline__ void zbuild_x1(ushort_t* zbuf, int bx, int ch,
                                          float4_ xr0, float4_ xr1,
                                          float4_ xr2, float4_ xr3)
{
    short8 a0, a1;
#pragma unroll
    for (int e = 0; e < 4; ++e) {
        a0[e]     = (short)f2bf(xr0[e]);
        a0[4 + e] = (short)f2bf(xr1[e]);
        a1[e]     = (short)f2bf(xr2[e]);
        a1[4 + e] = (short)f2bf(xr3[e]);
    }
    ushort_t* zh = zbuf + bx * ZPAD + ch * 16;
    ((short8*)zh)[0] = a0;
    ((short8*)zh)[1] = a1;
}

__global__ __launch_bounds__(256, 1)
void lstm_persistent(const float* __restrict__ x,
                     const float* __restrict__ Wf, const float* __restrict__ bf_,
                     const float* __restrict__ Wi, const float* __restrict__ bi_,
                     const float* __restrict__ Wo, const float* __restrict__ bo_,
                     const float* __restrict__ Wc, const float* __restrict__ bc_,
                     float* __restrict__ out,
                     uint_t* __restrict__ hpack)   // [2][NCL][H_][BPC] u32 {bf16<<16|tag}
{
    __shared__ ushort_t w_lds[4 * NKT * 512];     // 98304 B (B-frag order)
    __shared__ ushort_t z2[2][16 * ZPAD];         // 49664 B (z ping-pong)
    __shared__ float    gate_lds[4][16][20];      //  5120 B (per-wave transpose)
    __shared__ float    bias_lds[64];             //   256 B   (total 153344)

    const int tid  = threadIdx.x;
    const int lane = tid & 63;
    const int wv   = tid >> 6;          // wave 0..3 = col-tile owner
    const int cl   = blockIdx.x >> 5;   // cluster 0..3
    const int w    = blockIdx.x & 31;   // wg-in-cluster 0..31
    const int b0   = cl * BPC;          // first batch
    const int hc0  = w * 16;            // first h-col (global)

    // ---- one-time: repack W slice (fp32 global -> bf16 LDS, B-frag order) ----
    // frag: lane l holds B[k = kt*32 + (l>>4)*8 + j][n = ct*16 + (l&15)], j=0..7
    for (int idx = tid; idx < 4 * NKT * 64; idx += 256) {
        int blk   = idx >> 6;           // 0..95
        int ln    = idx & 63;
        int ct    = blk / NKT;
        int kt    = blk % NKT;
        int col16 = ln & 15;
        int kc    = ln >> 4;
        int j     = ct * 16 + col16;    // gemm col 0..63  (j = hc*4 + g)
        int hc    = j >> 2, g = j & 3;
        int gcol  = hc0 + hc;
        const float* Wsrc = (g == 0) ? Wf : ((g == 1) ? Wi : ((g == 2) ? Wo : Wc));
        int krow0 = kt * 32 + kc * 8;
        short8 v;
#pragma unroll
        for (int jj = 0; jj < 8; ++jj)
            v[jj] = (short)f2bf(Wsrc[(size_t)(krow0 + jj) * H_ + gcol]);
        *(short8*)(w_lds + blk * 512 + ln * 8) = v;
    }
    if (tid < 64) {
        int g = tid & 3, hc = tid >> 2;
        const float* bsrc = (g == 0) ? bf_ : ((g == 1) ? bi_ : ((g == 2) ? bo_ : bc_));
        bias_lds[tid] = bsrc[hc0 + hc];
    }
    __syncthreads();

    // ---- hoist this wave's 24 B-fragments (col-tile = wv) into registers ----
    short8 Bf[NKT];
#pragma unroll
    for (int kt = 0; kt < NKT; ++kt)
        Bf[kt] = *(const short8*)(w_lds + (wv * NKT + kt) * 512 + lane * 8);

    // ---- persistent state ----
    const int bx = tid & 15, ch = tid >> 4;   // z-build / gather mapping
    const float* xbase = x + (size_t)(b0 + bx) * (T_ * D_) + ch * 16;

    float4_ xr0, xr1, xr2, xr3;               // x(0) prefetch
    {
        const float4_* p = (const float4_*)xbase;
        xr0 = p[0]; xr1 = p[1]; xr2 = p[2]; xr3 = p[3];
    }
    zbuild_x1(z2[0], bx, ch, xr0, xr1, xr2, xr3);
#pragma unroll
    for (int q = 0; q < 32; ++q)              // h(0) = 0
        z2[0][bx * ZPAD + 256 + q * 16 + ch] = 0;
    __syncthreads();   // z(0) ready

    const int l15 = lane & 15, lk = lane >> 4;
    // gates/publish mapping: lane -> (batch = l15, h-col = hc0 + wv*4 + lk)
    const int hidx = hc0 + wv * 4 + lk;
    float c_reg = 0.0f;

    for (int t = 0; t < T_; ++t) {
        // ---- prefetch x(t+1) (HBM latency hides under MFMA+gates) ----
        if (t + 1 < T_) {
            const float4_* p = (const float4_*)(xbase + (size_t)(t + 1) * D_);
            xr0 = p[0]; xr1 = p[1]; xr2 = p[2]; xr3 = p[3];
        }

        // ---- MFMA: full K (24 kt), this wave's col-tile only; 2-acc ILP ----
        const ushort_t* zc = z2[t & 1] + l15 * ZPAD + lk * 8;
        f32x4 acA = {0.f, 0.f, 0.f, 0.f};
        f32x4 acB = {0.f, 0.f, 0.f, 0.f};
#pragma unroll
        for (int kt = 0; kt < NKT; kt += 2) {
            short8 a0 = *(const short8*)(zc + kt * 32);
            short8 a1 = *(const short8*)(zc + kt * 32 + 32);
            acA = __builtin_amdgcn_mfma_f32_16x16x32_bf16(a0, Bf[kt],     acA, 0, 0, 0);
            acB = __builtin_amdgcn_mfma_f32_16x16x32_bf16(a1, Bf[kt + 1], acB, 0, 0, 0);
        }
        f32x4 acc = acA + acB;

        // ---- in-wave transpose: acc (col=l15, rows lk*4+i) -> (batch, gate) ----
        *(f32x4*)&gate_lds[wv][l15][lk * 4] = acc;
        asm volatile("s_waitcnt lgkmcnt(0)" ::: "memory");
        __builtin_amdgcn_sched_barrier(0);

        float pre[4];
#pragma unroll
        for (int g = 0; g < 4; ++g)
            pre[g] = bias_lds[(wv * 4 + lk) * 4 + g] + gate_lds[wv][lk * 4 + g][l15];

        float fg = sigm_(pre[0]);
        float ig = sigm_(pre[1]);
        float og = sigm_(pre[2]);
        float cc = tanh_(pre[3]);
        c_reg = fmaf(c_reg, fg, cc * ig);
        float hout = og * tanh_(c_reg);

        // ---- publish h(t+1): coalesced (4 lanes -> 64B via [h][b] layout) ----
        {
            uint_t pk = ((uint_t)f2bf(hout) << 16) | (uint_t)((t + 1) & 0xffff);
            size_t ho = (size_t)(((t + 1) & 1) * NCL + cl) * (H_ * BPC)
                      + (size_t)hidx * BPC + l15;
            __hip_atomic_store(hpack + ho, pk,
                               __ATOMIC_RELAXED, __HIP_MEMORY_SCOPE_AGENT);
        }

        // ---- out store (off the critical path) ----
        out[((size_t)(b0 + l15) * T_ + t) * H_ + hidx] = hout;

        if (t + 1 < T_) {
            ushort_t* znext = z2[(t + 1) & 1];

            // x-part while producers' stores propagate
            zbuild_x1(znext, bx, ch, xr0, xr1, xr2, xr3);

            __builtin_amdgcn_s_sleep(SLEEP_PRE);

            // ---- gather h(t+1): 32 coalesced u32, tag-verified, sleep-paced ----
            const uint_t* hsrc = hpack + (size_t)(((t + 1) & 1) * NCL + cl) * (H_ * BPC);
            const uint_t want = (uint_t)((t + 1) & 0xffff);
            uint_t vv[32];
            uint_t mask = 0xffffffffu;
#pragma unroll
            for (int q = 0; q < 32; ++q)
                vv[q] = __hip_atomic_load(hsrc + q * 256 + tid,
                                          __ATOMIC_RELAXED, __HIP_MEMORY_SCOPE_AGENT);
            for (;;) {
#pragma unroll
                for (int q = 0; q < 32; ++q)
                    if (((mask >> q) & 1u) && (vv[q] & 0xffffu) == want) {
                        // idx = q*256+tid = h*16+b  ->  row b, col 256+h
                        znext[bx * ZPAD + 256 + q * 16 + ch] = (ushort_t)(vv[q] >> 16);
                        mask &= ~(1u << q);
                    }
                if (!mask) break;
                __builtin_amdgcn_s_sleep(SLEEP_RETRY);
#pragma unroll
                for (int q = 0; q < 32; ++q)
                    if ((mask >> q) & 1u)
                        vv[q] = __hip_atomic_load(hsrc + q * 256 + tid,
                                                  __ATOMIC_RELAXED, __HIP_MEMORY_SCOPE_AGENT);
            }

            // Safety of z ping-pong with ONE barrier: a wave writing znext here
            // is past barrier(t-1) and pre barrier(t); any wave still reading
            // z2[t&1] (MFMA of step t) is also pre barrier(t) -- different
            // buffer. A wave can only reach step t+1's writes to z2[t&1] after
            // barrier(t), which requires ALL waves done reading z2[t&1].
            __syncthreads();
        }
    }
}

extern "C" void kernel_launch(void* const* d_in, const int* in_sizes, int n_in,
                              void* d_out, int out_size, void* d_ws, size_t ws_size,
                              hipStream_t stream) {
    const float* x  = (const float*)d_in[0];
    const float* Wf = (const float*)d_in[1];
    const float* bf = (const float*)d_in[2];
    const float* Wi = (const float*)d_in[3];
    const float* bi = (const float*)d_in[4];
    const float* Wo = (const float*)d_in[5];
    const float* bo = (const float*)d_in[6];
    const float* Wc = (const float*)d_in[7];
    const float* bc = (const float*)d_in[8];
    float* out = (float*)d_out;

    // workspace: hpack [2][NCL][H_][BPC] u32 = 256 KB (tags must start != wanted)
    uint_t* hpack = (uint_t*)d_ws;
    hipMemsetAsync(d_ws, 0, (size_t)2 * NCL * H_ * BPC * sizeof(uint_t), stream);

    lstm_persistent<<<dim3(NCL * WPC), dim3(256), 0, stream>>>(
        x, Wf, bf, Wi, bi, Wo, bo, Wc, bc, out, hpack);
}

// Round 6
// 1520.377 us; speedup vs baseline: 1.6980x; 1.4561x over previous
//
#include <hip/hip_runtime.h>

// LSTM  B=64 T=512 D=256 H=512, fp32 in/out.
// Persistent kernel: 4 clusters x 32 WGs, 16 batches/cluster, 16 h-cols/WG.
// R6: R2's flag+drain handoff (empirically fastest) + R5's wave-owns-coltile
// local structure + clean vmcnt(0) drain (only publish stores outstanding) +
// XOR-swizzled unpadded z LDS (conflict-free) + u32-pair h exchange with
// fully-coalesced gather that writes straight to swizzled LDS + B-frags
// pinned in VGPRs via asm memory-clobber. 2 barriers/step.

#define B_   64
#define T_   512
#define D_   256
#define H_   512
#define NCL  4            // clusters
#define WPC  32           // workgroups per cluster
#define BPC  16           // batches per cluster
#define NKT  24           // K tiles of 32 (24*32 = 768 = D_+H_)
#define ZW   768          // z row width in u16 (no pad; XOR swizzle instead)

typedef __attribute__((ext_vector_type(8)))  short  short8;
typedef __attribute__((ext_vector_type(4)))  float  f32x4;
typedef __attribute__((ext_vector_type(4)))  float  float4_;
typedef unsigned short ushort_t;
typedef unsigned int   uint_t;

__device__ __forceinline__ ushort_t f2bf(float f) {           // RNE f32->bf16
    unsigned int u = __float_as_uint(f);
    u += 0x7FFFu + ((u >> 16) & 1u);
    return (ushort_t)(u >> 16);
}
__device__ __forceinline__ float sigm_(float x) { return 1.0f / (1.0f + __expf(-x)); }
__device__ __forceinline__ float tanh_(float x) {
    float a = fabsf(x);
    float e = __expf(-2.0f * a);
    float r = (1.0f - e) / (1.0f + e);
    return copysignf(r, x);
}

// z swizzle: element (row r, col c) lives at u16 index r*ZW + ((c>>3 ^ (r&7))<<3) + (c&7)

// build x-part of z: thread (bx,ch) -> row bx, cols ch*16..+16 (blocks 2ch, 2ch+1)
__device__ __forceinline__ void zbuild_x1(ushort_t* zbuf, int bx, int ch,
                                          float4_ xr0, float4_ xr1,
                                          float4_ xr2, float4_ xr3)
{
    short8 a0, a1;
#pragma unroll
    for (int e = 0; e < 4; ++e) {
        a0[e]     = (short)f2bf(xr0[e]);
        a0[4 + e] = (short)f2bf(xr1[e]);
        a1[e]     = (short)f2bf(xr2[e]);
        a1[4 + e] = (short)f2bf(xr3[e]);
    }
    const int s = bx & 7;
    *(short8*)(zbuf + bx * ZW + (((ch * 2    ) ^ s) << 3)) = a0;
    *(short8*)(zbuf + bx * ZW + (((ch * 2 + 1) ^ s) << 3)) = a1;
}

__global__ __launch_bounds__(256, 1)
void lstm_persistent(const float* __restrict__ x,
                     const float* __restrict__ Wf, const float* __restrict__ bf_,
                     const float* __restrict__ Wi, const float* __restrict__ bi_,
                     const float* __restrict__ Wo, const float* __restrict__ bo_,
                     const float* __restrict__ Wc, const float* __restrict__ bc_,
                     float* __restrict__ out,
                     uint_t* __restrict__ flags,
                     uint_t* __restrict__ hexch)  // [2][NCL][BPC][256] u32 {h_odd<<16|h_even}
{
    __shared__ ushort_t w_lds[4 * NKT * 512];     // 98304 B (B-frag order)
    __shared__ ushort_t z2[2][16 * ZW];           // 49152 B (z ping-pong, swizzled)
    __shared__ float    gate_lds[4][16][20];      //  5120 B (per-wave transpose)
    __shared__ float    bias_lds[64];             //   256 B   (total 152832)

    const int tid  = threadIdx.x;
    const int lane = tid & 63;
    const int wv   = tid >> 6;          // wave 0..3 = col-tile owner
    const int cl   = blockIdx.x >> 5;   // cluster 0..3
    const int w    = blockIdx.x & 31;   // wg-in-cluster 0..31
    const int b0   = cl * BPC;          // first batch
    const int hc0  = w * 16;            // first h-col (global)

    // ---- one-time: repack W slice (fp32 global -> bf16 LDS, B-frag order) ----
    // frag: lane l holds B[k = kt*32 + (l>>4)*8 + j][n = ct*16 + (l&15)], j=0..7
    for (int idx = tid; idx < 4 * NKT * 64; idx += 256) {
        int blk   = idx >> 6;           // 0..95
        int ln    = idx & 63;
        int ct    = blk / NKT;
        int kt    = blk % NKT;
        int col16 = ln & 15;
        int kc    = ln >> 4;
        int j     = ct * 16 + col16;    // gemm col 0..63  (j = hc*4 + g)
        int hc    = j >> 2, g = j & 3;
        int gcol  = hc0 + hc;
        const float* Wsrc = (g == 0) ? Wf : ((g == 1) ? Wi : ((g == 2) ? Wo : Wc));
        int krow0 = kt * 32 + kc * 8;
        short8 v;
#pragma unroll
        for (int jj = 0; jj < 8; ++jj)
            v[jj] = (short)f2bf(Wsrc[(size_t)(krow0 + jj) * H_ + gcol]);
        *(short8*)(w_lds + blk * 512 + ln * 8) = v;
    }
    if (tid < 64) {
        int g = tid & 3, hc = tid >> 2;
        const float* bsrc = (g == 0) ? bf_ : ((g == 1) ? bi_ : ((g == 2) ? bo_ : bc_));
        bias_lds[tid] = bsrc[hc0 + hc];
    }

    // ---- persistent thread mappings ----
    const int bx = tid & 15, ch = tid >> 4;   // z-build / staging mapping
    const int l15 = lane & 15, lk = lane >> 4;
    const int hidx = hc0 + wv * 4 + lk;       // gates/publish: (batch=l15, hcol=hidx)
    const float* xbase = x + (size_t)(b0 + bx) * (T_ * D_) + ch * 16;

    // prefetch x(0), build z(0) = [x(0) | h=0]
    float4_ xr0, xr1, xr2, xr3;
    {
        const float4_* p = (const float4_*)xbase;
        xr0 = p[0]; xr1 = p[1]; xr2 = p[2]; xr3 = p[3];
    }
    zbuild_x1(z2[0], bx, ch, xr0, xr1, xr2, xr3);
    {
        const int blk0 = 32 + (tid >> 2), off = (tid & 3) * 2;
#pragma unroll
        for (int r = 0; r < 16; ++r)
            *(uint_t*)(z2[0] + r * ZW + ((blk0 ^ (r & 7)) << 3) + off) = 0u;
    }
    __syncthreads();   // w_lds, bias, z(0) ready

    // ---- hoist this wave's 24 B-fragments (col-tile wv) into registers ----
    short8 Bf[NKT];
#pragma unroll
    for (int kt = 0; kt < NKT; ++kt)
        Bf[kt] = *(const short8*)(w_lds + (wv * NKT + kt) * 512 + lane * 8);
    // memory clobber: compiler may no longer re-load Bf from w_lds (the asm
    // "might have written it") -> the 96 VGPRs must stay live.
    asm volatile("" ::: "memory");

    float c_reg = 0.0f;
    const int s7 = l15 & 7;

    for (int t = 0; t < T_; ++t) {
        // ---- prefetch x(t+1): consumed by zbuild AFTER the flag store ----
        if (t + 1 < T_) {
            const float4_* p = (const float4_*)(xbase + (size_t)(t + 1) * D_);
            xr0 = p[0]; xr1 = p[1]; xr2 = p[2]; xr3 = p[3];
        }

        // ---- MFMA: full K (24 kt), this wave's col-tile; 4-acc ILP ----
        const ushort_t* zr = z2[t & 1] + l15 * ZW;
        f32x4 ac0 = {0.f, 0.f, 0.f, 0.f};
        f32x4 ac1 = {0.f, 0.f, 0.f, 0.f};
        f32x4 ac2 = {0.f, 0.f, 0.f, 0.f};
        f32x4 ac3 = {0.f, 0.f, 0.f, 0.f};
#pragma unroll
        for (int kt = 0; kt < NKT; kt += 4) {
            short8 a0 = *(const short8*)(zr + ((((kt + 0) * 4 + lk) ^ s7) << 3));
            short8 a1 = *(const short8*)(zr + ((((kt + 1) * 4 + lk) ^ s7) << 3));
            short8 a2 = *(const short8*)(zr + ((((kt + 2) * 4 + lk) ^ s7) << 3));
            short8 a3 = *(const short8*)(zr + ((((kt + 3) * 4 + lk) ^ s7) << 3));
            ac0 = __builtin_amdgcn_mfma_f32_16x16x32_bf16(a0, Bf[kt + 0], ac0, 0, 0, 0);
            ac1 = __builtin_amdgcn_mfma_f32_16x16x32_bf16(a1, Bf[kt + 1], ac1, 0, 0, 0);
            ac2 = __builtin_amdgcn_mfma_f32_16x16x32_bf16(a2, Bf[kt + 2], ac2, 0, 0, 0);
            ac3 = __builtin_amdgcn_mfma_f32_16x16x32_bf16(a3, Bf[kt + 3], ac3, 0, 0, 0);
        }
        f32x4 acc = (ac0 + ac1) + (ac2 + ac3);

        // ---- in-wave transpose: acc (batch=lk*4+i, gemmcol=l15) -> per-lane gates ----
        *(f32x4*)&gate_lds[wv][l15][lk * 4] = acc;
        asm volatile("s_waitcnt lgkmcnt(0)" ::: "memory");
        __builtin_amdgcn_sched_barrier(0);

        float pre[4];
#pragma unroll
        for (int g = 0; g < 4; ++g)
            pre[g] = bias_lds[(wv * 4 + lk) * 4 + g] + gate_lds[wv][lk * 4 + g][l15];

        float fg = sigm_(pre[0]);
        float ig = sigm_(pre[1]);
        float og = sigm_(pre[2]);
        float cc = tanh_(pre[3]);
        c_reg = fmaf(c_reg, fg, cc * ig);
        float hout = og * tanh_(c_reg);

        // ---- publish h(t+1): even-lk lanes store packed u32 pair ----
        float hpart = __shfl_xor(hout, 16);   // partner has hidx^1
        if (!(lk & 1)) {
            uint_t pk = ((uint_t)f2bf(hpart) << 16) | (uint_t)f2bf(hout);
            size_t ho = (size_t)(((t + 1) & 1) * NCL + cl) * (BPC * 256)
                      + (size_t)l15 * 256 + (hc0 >> 1) + wv * 2 + (lk >> 1);
            __hip_atomic_store(hexch + ho, pk,
                               __ATOMIC_RELAXED, __HIP_MEMORY_SCOPE_AGENT);
        }

        // ---- clean drain: ONLY the publish stores are outstanding here ----
        asm volatile("s_waitcnt vmcnt(0)" ::: "memory");
        __syncthreads();   // (A) all waves' publishes at coherence point
        if (tid == 0)
            __hip_atomic_store(flags + cl * WPC + w, (uint_t)(t + 1),
                               __ATOMIC_RELAXED, __HIP_MEMORY_SCOPE_AGENT);

        // ---- off-critical-path work while other WGs' flags propagate ----
        out[((size_t)(b0 + l15) * T_ + t) * H_ + hidx] = hout;

        if (t + 1 < T_) {
            ushort_t* zn = z2[(t + 1) & 1];
            zbuild_x1(zn, bx, ch, xr0, xr1, xr2, xr3);

            // ---- sleep-paced flag poll (32 flags, 2 cache lines) ----
            if (lane < WPC) {
                const uint_t* fp = flags + cl * WPC + lane;
                while (__hip_atomic_load(fp, __ATOMIC_RELAXED,
                                         __HIP_MEMORY_SCOPE_AGENT) <= (uint_t)t)
                    __builtin_amdgcn_s_sleep(1);
            }

            // ---- gather: 16 coalesced u32 loads -> direct swizzled LDS u32 stores ----
            const uint_t* hs = hexch + (size_t)(((t + 1) & 1) * NCL + cl) * (BPC * 256);
            uint_t hv[16];
#pragma unroll
            for (int q = 0; q < 16; ++q)
                hv[q] = __hip_atomic_load(hs + q * 256 + tid,
                                          __ATOMIC_RELAXED, __HIP_MEMORY_SCOPE_AGENT);
            // thread holds h-cols {2*tid, 2*tid+1} for batches q=0..15
            const int blk0 = 32 + (tid >> 2), off = (tid & 3) * 2;
#pragma unroll
            for (int r = 0; r < 16; ++r)
                *(uint_t*)(zn + r * ZW + ((blk0 ^ (r & 7)) << 3) + off) = hv[r];
        }

        __syncthreads();   // (B) z(t+1) ready; z(t) free for overwrite next iter
    }
}

extern "C" void kernel_launch(void* const* d_in, const int* in_sizes, int n_in,
                              void* d_out, int out_size, void* d_ws, size_t ws_size,
                              hipStream_t stream) {
    const float* x  = (const float*)d_in[0];
    const float* Wf = (const float*)d_in[1];
    const float* bf = (const float*)d_in[2];
    const float* Wi = (const float*)d_in[3];
    const float* bi = (const float*)d_in[4];
    const float* Wo = (const float*)d_in[5];
    const float* bo = (const float*)d_in[6];
    const float* Wc = (const float*)d_in[7];
    const float* bc = (const float*)d_in[8];
    float* out = (float*)d_out;

    // workspace: [0,512)   flags (4 clusters x 32 u32)  -- must start at 0
    //            [1024, +131072) hexch [2][NCL][BPC][256] u32
    uint_t* flags = (uint_t*)d_ws;
    uint_t* hexch = (uint_t*)((char*)d_ws + 1024);

    hipMemsetAsync(d_ws, 0, 512, stream);   // zero flags only (hexch gated by flags)

    lstm_persistent<<<dim3(NCL * WPC), dim3(256), 0, stream>>>(
        x, Wf, bf, Wi, bi, Wo, bo, Wc, bc, out, flags, hexch);
}